// Round 14
// baseline (233.145 us; speedup 1.0000x reference)
//
#include <hip/hip_runtime.h>

// SpectralConv2d: B=16, C_in=C_out=64, H=W=256, k=16.
// Retained modes: rows {0..15, 240..255} x cols {0..15} -> direct sparse DFTs.
//
// Pipeline (fp32):
//  k_fwd1    : x-DFT per (b,c,chunk), LDS-FREE (direct global float4 streams,
//              L1 absorbs the 8-way row broadcast) [blocks 0..8191]
//              + repack R'[mw][co] [blocks 8192..8703] (independent).
//  k_fwd2    : y-DFT, split 2 blocks/image (yy-halves; U = U0 + U1 exact)
//  k_cgemm   : per mw: V[mw][bo] = sum_c (U0+U1)[b][c]*R'[c][o]
//  k_inv     : inverse y-DFT + quad-symmetric x reconstruction -> out

#define B_    16
#define H_    256
#define W_    256

// ws float offsets
#define OFF_CT 0
#define OFF_ST 256
#define OFF_RP 512
#define RP_SZ  (512*4096*2)                  // 4,194,304 floats ([mw][co] float2)
#define OFF_U0 (OFF_RP + RP_SZ)              // 4,194,816  ([bc][mw] float2)
#define U_SZ   (1024*512*2)                  // 1,048,576
#define OFF_V  (OFF_U0 + U_SZ)               // 5,243,392  ([mw][bo] float2)
#define V_SZ   (512*1024*2)                  // 1,048,576
#define OFF_U1 (OFF_V + V_SZ)                // 6,291,968  ([bc][mw] float2)
// total ws: 7,340,544 floats = 29.4 MB

#define TWOPI_256 0.024543692606170259f      // 2*pi/256

// x-DFT + repack. grid 8704: blocks 0..8191 = (bc,chunk) x-DFT; 8192.. = repack.
// fwd1 (LDS-free): lane = (r8<<3)|h handles row 8w+r8, modes (2h,2h+1).
// Reads 4 global float4-streams (x, x+64, x+128, x+192); the 8 h-threads of a
// row issue identical addresses (coalesced broadcast); each 64B line is fully
// consumed inside one unroll-4 window -> L1-resident reuse, L2 traffic = u once.
__global__ __launch_bounds__(256) void k_fwd1(const float* __restrict__ u,
                                              const float* __restrict__ wpr,
                                              const float* __restrict__ wpi,
                                              const float* __restrict__ wnr,
                                              const float* __restrict__ wni,
                                              float* __restrict__ ws,
                                              float* __restrict__ P) {
    int t = threadIdx.x;

    if (blockIdx.x >= 8192) {                        // ---- repack branch ----
        int mw = blockIdx.x - 8192;                  // 0..511 = m*16 + wmc
        int m = mw >> 4, wmc = mw & 15;
        const float* wr; const float* wi; int i;
        if (m < 16) { wr = wpr; wi = wpi; i = m; }
        else        { wr = wnr; wi = wni; i = m - 16; }
        if (mw == 0) {                               // twiddle tables for k_inv
            double a = 2.0 * 3.14159265358979323846 * (double)t / 256.0;
            ws[OFF_CT + t] = (float)cos(a);
            ws[OFF_ST + t] = (float)sin(a);
        }
        float norm = (wmc == 0 ? 1.f : 2.f) * (1.f / 65536.f);
        int off = i * 16 + wmc;
        float2* rp = (float2*)(ws + OFF_RP) + (size_t)mw * 4096;
        #pragma unroll
        for (int k = 0; k < 16; ++k) {
            int co = t + 256 * k;
            rp[co] = make_float2(wr[(size_t)co * 256 + off] * norm,
                                 wi[(size_t)co * 256 + off] * norm);
        }
        return;
    }

    int bc = blockIdx.x >> 3, ch = blockIdx.x & 7;
    int lane = t & 63, w = t >> 6;
    int h = lane & 7, r8 = lane >> 3;
    int rowc = w * 8 + r8;
    const float* rowp = u + (size_t)bc * 65536 + ch * 8192 + rowc * 256;

    int wm0 = 2 * h, wm1 = wm0 + 1;
    float s0v, c0v, s1v, c1v;
    __sincosf(TWOPI_256 * (float)wm0, &s0v, &c0v);
    __sincosf(TWOPI_256 * (float)wm1, &s1v, &c1v);
    float r0r = c0v, r0i = -s0v;                     // e^{-2pi i wm0/256}
    float r1r = c1v, r1i = -s1v;
    float bs  = (h & 1) ? -1.f : 1.f;                // (-i)^(2h*k) = (-1)^(hk)
    float dsg = (h & 1) ? 1.f : -1.f;                // g1 = c -/+ i d

    float p0r = 0.f, p0i = 0.f, p1r = 0.f, p1i = 0.f;
    float t0r = 1.f, t0i = 0.f, t1r = 1.f, t1i = 0.f;

    #pragma unroll 4
    for (int bat = 0; bat < 16; ++bat) {
        const float4* rp4 = (const float4*)(rowp + 4 * bat);
        float4 q0 = rp4[0];                          // x = 4bat ..
        float4 q1 = rp4[16];                         // +64
        float4 q2 = rp4[32];                         // +128
        float4 q3 = rp4[48];                         // +192
        #define PROC_(u0, u1, u2, u3) {                                   \
            float a_ = (u0) + (u2), b_ = (u1) + (u3);                     \
            float c_ = (u0) - (u2), d_ = (u1) - (u3);                     \
            float g0 = fmaf(bs, b_, a_);                                  \
            float g1r = c_, g1i = dsg * d_;                               \
            p0r = fmaf(g0, t0r, p0r);                                     \
            p0i = fmaf(g0, t0i, p0i);                                     \
            p1r = fmaf(g1r, t1r, fmaf(-g1i, t1i, p1r));                   \
            p1i = fmaf(g1r, t1i, fmaf( g1i, t1r, p1i));                   \
            float n0r = t0r * r0r - t0i * r0i;                            \
            float n0i = t0r * r0i + t0i * r0r;                            \
            float n1r = t1r * r1r - t1i * r1i;                            \
            float n1i = t1r * r1i + t1i * r1r;                            \
            t0r = n0r; t0i = n0i; t1r = n1r; t1i = n1i; }
        PROC_(q0.x, q1.x, q2.x, q3.x)
        PROC_(q0.y, q1.y, q2.y, q3.y)
        PROC_(q0.z, q1.z, q2.z, q3.z)
        PROC_(q0.w, q1.w, q2.w, q3.w)
        #undef PROC_
    }
    int y = ch * 32 + rowc;
    ((float4*)P)[((size_t)bc * 256 + y) * 8 + h] = make_float4(p0r, p0i, p1r, p1i);
}

// y-DFT. grid 2048 = (bc, half). Half hh sums yy in [32hh, 32hh+32) of the
// quarter-turn groups (y = yy+64g); U = U0 + U1 exactly. Seed phase
// e^{-2pi i f*32hh/256} is identical for f=m1 and f=m1-16 (mod 256).
__global__ __launch_bounds__(256) void k_fwd2(const float* __restrict__ P,
                                              float* __restrict__ ws) {
    __shared__ float Pl[4][32][36];                  // 18.4 KB
    int t = threadIdx.x;
    int bc = blockIdx.x >> 1, hh = blockIdx.x & 1;
    const float4* Pg = (const float4*)(P + (size_t)bc * 8192);
    #pragma unroll
    for (int k = 0; k < 4; ++k) {
        int idx = t + 256 * k;                       // 0..1023
        int g = idx >> 8, j = (idx >> 3) & 31, q = idx & 7;
        *(float4*)&Pl[g][j][4 * q] = Pg[(size_t)(hh * 32 + j + 64 * g) * 8 + q];
    }
    __syncthreads();

    int wm = t & 15;
    int v  = t >> 4;
    int m1 = ((v & 3) << 2) | (v >> 2);              // md = m1&3 uniform per wave
    float sv, cv;
    __sincosf(TWOPI_256 * (float)m1, &sv, &cv);
    float r1r = cv, r1i = -sv;                       // e^{-2pi i m1/256}
    __sincosf(TWOPI_256 * (float)(m1 - 16), &sv, &cv);
    float r2r = cv, r2i = -sv;                       // e^{-2pi i (m1-16)/256}
    int a0 = (m1 * 32 * hh) & 255;                   // seed phase (both modes)
    __sincosf(TWOPI_256 * (float)a0, &sv, &cv);
    float t1r = cv, t1i = -sv, t2r = cv, t2i = -sv;
    float U1r = 0.f, U1i = 0.f, U2r = 0.f, U2i = 0.f;
    int md = m1 & 3;
    #pragma unroll 4
    for (int j = 0; j < 32; ++j) {
        float2 P0 = *(float2*)&Pl[0][j][2 * wm];
        float2 P1 = *(float2*)&Pl[1][j][2 * wm];
        float2 P2 = *(float2*)&Pl[2][j][2 * wm];
        float2 P3 = *(float2*)&Pl[3][j][2 * wm];
        float ar = P0.x + P2.x, ai = P0.y + P2.y;
        float br = P1.x + P3.x, bi = P1.y + P3.y;
        float cr = P0.x - P2.x, ci = P0.y - P2.y;
        float dr = P1.x - P3.x, di = P1.y - P3.y;
        float gr, gi;
        if (md == 0)      { gr = ar + br; gi = ai + bi; }
        else if (md == 1) { gr = cr + di; gi = ci - dr; }   // g = c - i d
        else if (md == 2) { gr = ar - br; gi = ai - bi; }
        else              { gr = cr - di; gi = ci + dr; }   // g = c + i d
        U1r = fmaf(gr, t1r, fmaf(-gi, t1i, U1r));
        U1i = fmaf(gr, t1i, fmaf( gi, t1r, U1i));
        U2r = fmaf(gr, t2r, fmaf(-gi, t2i, U2r));
        U2i = fmaf(gr, t2i, fmaf( gi, t2r, U2i));
        float n1r = t1r * r1r - t1i * r1i, n1i = t1r * r1i + t1i * r1r;
        float n2r = t2r * r2r - t2i * r2i, n2i = t2r * r2i + t2i * r2r;
        t1r = n1r; t1i = n1i; t2r = n2r; t2i = n2i;
    }
    float2* U = (float2*)(ws + (hh ? OFF_U1 : OFF_U0)) + (size_t)bc * 512;
    U[m1 * 16 + wm]        = make_float2(U1r, U1i);
    U[(m1 + 16) * 16 + wm] = make_float2(U2r, U2i);
}

// per-mode channel GEMM: grid 512 = mw. Combines U = U0 + U1 on load.
__global__ __launch_bounds__(256) void k_cgemm(float* __restrict__ ws) {
    __shared__ float2 Ul[1024];
    int mw = blockIdx.x, t = threadIdx.x;
    const float2* Ug0 = (const float2*)(ws + OFF_U0);
    const float2* Ug1 = (const float2*)(ws + OFF_U1);
    #pragma unroll
    for (int k = 0; k < 4; ++k) {
        int bcv = t + 256 * k;
        float2 a = Ug0[(size_t)bcv * 512 + mw];
        float2 b = Ug1[(size_t)bcv * 512 + mw];
        Ul[bcv] = make_float2(a.x + b.x, a.y + b.y);
    }
    __syncthreads();
    int o = t & 63, bq = t >> 6;
    const float2* rp = (const float2*)(ws + OFF_RP) + (size_t)mw * 4096;  // [mw][co]
    float ar[4] = {0.f, 0.f, 0.f, 0.f}, ai[4] = {0.f, 0.f, 0.f, 0.f};
    #pragma unroll 4
    for (int c = 0; c < 64; ++c) {
        float2 R = rp[c * 64 + o];                         // coalesced 512B
        #pragma unroll
        for (int j = 0; j < 4; ++j) {
            float2 Uv = Ul[(bq * 4 + j) * 64 + c];         // wave-uniform -> broadcast
            ar[j] = fmaf(Uv.x, R.x, fmaf(-Uv.y, R.y, ar[j]));
            ai[j] = fmaf(Uv.x, R.y, fmaf( Uv.y, R.x, ai[j]));
        }
    }
    float2* Vg = (float2*)(ws + OFF_V) + (size_t)mw * 1024;  // [mw][bo]
    #pragma unroll
    for (int j = 0; j < 4; ++j)
        Vg[(bq * 4 + j) * 64 + o] = make_float2(ar[j], ai[j]);  // coalesced
}

// inverse. grid 4096 = (bo, q). Stage 5 quad-symmetric (R13, verified).
__global__ __launch_bounds__(256) void k_inv(const float* __restrict__ ws,
                                             float* __restrict__ out) {
    __shared__ float Vl[16][68];
    __shared__ float Tl[4][16][36];
    __shared__ float ct[256], st[256];
    int t = threadIdx.x;
    int bo = blockIdx.x >> 2, q = blockIdx.x & 3;
    ct[t] = ws[OFF_CT + t];
    st[t] = ws[OFF_ST + t];
    {
        const float2* Vg = (const float2*)(ws + OFF_V);
        float2 v0 = Vg[(size_t)t * 1024 + bo];
        float2 v1 = Vg[(size_t)(t + 256) * 1024 + bo];
        int m = t >> 4, wmv = t & 15;
        Vl[wmv][2 * m]        = v0.x;  Vl[wmv][2 * m + 1]        = v0.y;
        Vl[wmv][2 * (m + 16)] = v1.x;  Vl[wmv][2 * (m + 16) + 1] = v1.y;
    }
    __syncthreads();

    // stage 4: T[y0+64g] = sum_m V[m] e^{+2pi i f y0/256} * i^(f g)
    int wm4 = t & 15, yb = t >> 4;
    int y0 = q * 16 + yb;
    float vr[32], vi[32];
    #pragma unroll
    for (int m = 0; m < 32; ++m) { vr[m] = Vl[wm4][2 * m]; vi[m] = Vl[wm4][2 * m + 1]; }
    float cy = ct[y0], sy = st[y0];
    float T0r=0,T0i=0,T1r=0,T1i=0,T2r=0,T2i=0,T3r=0,T3i=0;
    float tr = 1.f, ti = 0.f;
    #pragma unroll
    for (int m = 0; m < 32; ++m) {
        if (m == 16) {
            int i16 = (4096 - 16 * y0) & 255;          // e^{-2pi i 16 y0/256}
            tr = ct[i16]; ti = st[i16];
        }
        float hr = vr[m] * tr - vi[m] * ti;
        float hi = vr[m] * ti + vi[m] * tr;
        const int md = m & 3;
        T0r += hr; T0i += hi;
        if (md == 0)      { T1r += hr; T1i += hi; T2r += hr; T2i += hi; T3r += hr; T3i += hi; }
        else if (md == 1) { T1r -= hi; T1i += hr; T2r -= hr; T2i -= hi; T3r += hi; T3i -= hr; }
        else if (md == 2) { T1r -= hr; T1i -= hi; T2r += hr; T2i += hi; T3r -= hr; T3i -= hi; }
        else              { T1r += hi; T1i -= hr; T2r -= hr; T2i -= hi; T3r -= hi; T3i += hr; }
        float nr = tr * cy - ti * sy, ni = tr * sy + ti * cy;
        tr = nr; ti = ni;
    }
    Tl[0][yb][wm4] = T0r; Tl[0][yb][16 + wm4] = T0i;
    Tl[1][yb][wm4] = T1r; Tl[1][yb][16 + wm4] = T1i;
    Tl[2][yb][wm4] = T2r; Tl[2][yb][16 + wm4] = T2i;
    Tl[3][yb][wm4] = T3r; Tl[3][yb][16 + wm4] = T3i;
    __syncthreads();

    // stage 5: quad-symmetric x reconstruction
    int l = t & 63, wv = t >> 6;
    float c0[16], s0[16];
    #pragma unroll
    for (int wm = 0; wm < 16; ++wm) {
        int idx = (wm * l) & 255;
        c0[wm] = ct[idx]; s0[wm] = st[idx];
    }
    float* ob = out + (size_t)bo * 65536;
    for (int yi = 0; yi < 16; ++yi) {
        int y = wv * 64 + q * 16 + yi;
        float TR[16], TI[16];
        const float4* rowv = (const float4*)&Tl[wv][yi][0];
        #pragma unroll
        for (int qq = 0; qq < 4; ++qq) {
            float4 a = rowv[qq];
            TR[4*qq]=a.x; TR[4*qq+1]=a.y; TR[4*qq+2]=a.z; TR[4*qq+3]=a.w;
            float4 b = rowv[qq + 4];
            TI[4*qq]=b.x; TI[4*qq+1]=b.y; TI[4*qq+2]=b.z; TI[4*qq+3]=b.w;
        }
        float Pv = 0.f, Qv = 0.f, Rv = 0.f, Sv = 0.f;
        #pragma unroll
        for (int wm = 0; wm < 16; wm += 2) {
            Pv = fmaf(TR[wm],     c0[wm],     Pv);
            Rv = fmaf(TI[wm],     s0[wm],     Rv);
            Qv = fmaf(TR[wm + 1], c0[wm + 1], Qv);
            Sv = fmaf(TI[wm + 1], s0[wm + 1], Sv);
        }
        float Ac = Pv + Qv, Bs = Rv + Sv;
        float Dc = Pv - Qv, Es = Rv - Sv;
        float* row = ob + (size_t)y * 256;
        row[l]               = Ac - Bs;        // x = l
        row[(256 - l) & 255] = Ac + Bs;        // x = 256-l
        row[128 + l]         = Dc - Es;        // x = 128+l
        row[128 - l]         = Dc + Es;        // x = 128-l
        float E0 = TR[0] + TR[4] + TR[8]  + TR[12];
        float E2 = TR[2] + TR[6] + TR[10] + TR[14];
        float O1 = TI[1] + TI[5] + TI[9]  + TI[13];
        float O3 = TI[3] + TI[7] + TI[11] + TI[15];
        float EC = E0 - E2, OC = O1 - O3;
        if (l == 0) {
            row[64]  = EC - OC;
            row[192] = EC + OC;
        }
    }
}

extern "C" void kernel_launch(void* const* d_in, const int* in_sizes, int n_in,
                              void* d_out, int out_size, void* d_ws, size_t ws_size,
                              hipStream_t stream) {
    const float* u   = (const float*)d_in[0];
    const float* wpr = (const float*)d_in[1];
    const float* wpi = (const float*)d_in[2];
    const float* wnr = (const float*)d_in[3];
    const float* wni = (const float*)d_in[4];
    float* out = (float*)d_out;
    float* ws  = (float*)d_ws;
    float* P   = (float*)d_out;            // 33.5 MB scratch in d_out (overwritten by k_inv)

    hipLaunchKernelGGL(k_fwd1,  dim3(8704), dim3(256), 0, stream, u, wpr, wpi, wnr, wni, ws, P);
    hipLaunchKernelGGL(k_fwd2,  dim3(2048), dim3(256), 0, stream, P, ws);
    hipLaunchKernelGGL(k_cgemm, dim3(512),  dim3(256), 0, stream, ws);
    hipLaunchKernelGGL(k_inv,   dim3(4096), dim3(256), 0, stream, ws, out);
}

// Round 15
// 211.086 us; speedup vs baseline: 1.1045x; 1.1045x over previous
//
#include <hip/hip_runtime.h>

// SpectralConv2d: B=16, C_in=C_out=64, H=W=256, k=16.
// Retained modes: rows {0..15, 240..255} x cols {0..15} -> direct sparse DFTs.
//
// Pipeline (fp32):
//  k_fwd1    : x-DFT per (b,c,chunk) with global_load_lds staging (R13-proven;
//              deep-MLP stage then conflict-free b128 reads) [blocks 0..8191]
//              + repack R'[mw][co] [blocks 8192..8703] (independent).
//  k_fwd2    : y-DFT, split 2 blocks/image (yy-halves; U = U0 + U1 exact)
//  k_cgemm   : per mw: V[mw][bo] = sum_c (U0+U1)[b][c]*R'[c][o]
//  k_inv     : inverse y-DFT + quad-symmetric x reconstruction -> out

#define B_    16
#define H_    256
#define W_    256

// ws float offsets
#define OFF_CT 0
#define OFF_ST 256
#define OFF_RP 512
#define RP_SZ  (512*4096*2)                  // 4,194,304 floats ([mw][co] float2)
#define OFF_U0 (OFF_RP + RP_SZ)              // 4,194,816  ([bc][mw] float2)
#define U_SZ   (1024*512*2)                  // 1,048,576
#define OFF_V  (OFF_U0 + U_SZ)               // 5,243,392  ([mw][bo] float2)
#define V_SZ   (512*1024*2)                  // 1,048,576
#define OFF_U1 (OFF_V + V_SZ)                // 6,291,968  ([bc][mw] float2)
// total ws: 7,340,544 floats = 29.4 MB

#define UTP   260                            // ut row pitch (floats): conflict-free b128 rows
#define TWOPI_256 0.024543692606170259f      // 2*pi/256

typedef const __attribute__((address_space(1))) void g_void;
typedef __attribute__((address_space(3))) void l_void;

__device__ __forceinline__ void load_lds16(const float* g, float* l) {
    __builtin_amdgcn_global_load_lds((g_void*)g, (l_void*)l, 16, 0, 0);
}

// x-DFT + repack. grid 8704: blocks 0..8191 = (bc,chunk) x-DFT; 8192.. = repack.
// fwd1: wave-private staging (no block barriers), per-wave vmcnt(0), sincosf
// seeds; lane = (r8<<3)|h: row 8w+r8, modes (2h,2h+1); 16 bats x 4
// ds_read_b128 (conflict-free at pitch 260, 8-way broadcast); quarter-turn
// x = j+64k with twiddle(x)=twiddle(j)*(-i)^(wm*k), scalar state.
__global__ __launch_bounds__(256) void k_fwd1(const float* __restrict__ u,
                                              const float* __restrict__ wpr,
                                              const float* __restrict__ wpi,
                                              const float* __restrict__ wnr,
                                              const float* __restrict__ wni,
                                              float* __restrict__ ws,
                                              float* __restrict__ P) {
    __shared__ __align__(16) float ut[32][UTP];      // 33.3 KB
    int t = threadIdx.x;

    if (blockIdx.x >= 8192) {                        // ---- repack branch ----
        int mw = blockIdx.x - 8192;                  // 0..511 = m*16 + wmc
        int m = mw >> 4, wmc = mw & 15;
        const float* wr; const float* wi; int i;
        if (m < 16) { wr = wpr; wi = wpi; i = m; }
        else        { wr = wnr; wi = wni; i = m - 16; }
        if (mw == 0) {                               // twiddle tables for k_inv
            double a = 2.0 * 3.14159265358979323846 * (double)t / 256.0;
            ws[OFF_CT + t] = (float)cos(a);
            ws[OFF_ST + t] = (float)sin(a);
        }
        float norm = (wmc == 0 ? 1.f : 2.f) * (1.f / 65536.f);
        int off = i * 16 + wmc;
        float2* rp = (float2*)(ws + OFF_RP) + (size_t)mw * 4096;
        #pragma unroll
        for (int k = 0; k < 16; ++k) {
            int co = t + 256 * k;
            rp[co] = make_float2(wr[(size_t)co * 256 + off] * norm,
                                 wi[(size_t)co * 256 + off] * norm);
        }
        return;
    }

    int bc = blockIdx.x >> 3, ch = blockIdx.x & 7;
    const float* ub = u + (size_t)bc * 65536 + ch * 8192;
    int lane = t & 63, w = t >> 6;
    #pragma unroll
    for (int k = 0; k < 8; ++k)
        load_lds16(ub + (w * 8 + k) * 256 + lane * 4, &ut[w * 8 + k][0]);

    int h = lane & 7, r8 = lane >> 3;
    int rowc = w * 8 + r8;
    int wm0 = 2 * h, wm1 = wm0 + 1;
    float s0v, c0v, s1v, c1v;
    __sincosf(TWOPI_256 * (float)wm0, &s0v, &c0v);
    __sincosf(TWOPI_256 * (float)wm1, &s1v, &c1v);
    float r0r = c0v, r0i = -s0v;                     // e^{-2pi i wm0/256}
    float r1r = c1v, r1i = -s1v;
    float bs  = (h & 1) ? -1.f : 1.f;                // (-i)^(2h*k) = (-1)^(hk)
    float dsg = (h & 1) ? 1.f : -1.f;                // g1 = c -/+ i d

    float p0r = 0.f, p0i = 0.f, p1r = 0.f, p1i = 0.f;
    float t0r = 1.f, t0i = 0.f, t1r = 1.f, t1i = 0.f;

    // wait ONLY this wave's 8 staging loads; no cross-wave dependency.
    asm volatile("s_waitcnt vmcnt(0)" ::: "memory");

    const float* rowp = &ut[rowc][0];
    #pragma unroll 4
    for (int bat = 0; bat < 16; ++bat) {
        const float* rp = rowp + 4 * bat;
        float4 q0 = *(const float4*)(rp);
        float4 q1 = *(const float4*)(rp + 64);
        float4 q2 = *(const float4*)(rp + 128);
        float4 q3 = *(const float4*)(rp + 192);
        #define PROC_(u0, u1, u2, u3) {                                   \
            float a_ = (u0) + (u2), b_ = (u1) + (u3);                     \
            float c_ = (u0) - (u2), d_ = (u1) - (u3);                     \
            float g0 = fmaf(bs, b_, a_);                                  \
            float g1r = c_, g1i = dsg * d_;                               \
            p0r = fmaf(g0, t0r, p0r);                                     \
            p0i = fmaf(g0, t0i, p0i);                                     \
            p1r = fmaf(g1r, t1r, fmaf(-g1i, t1i, p1r));                   \
            p1i = fmaf(g1r, t1i, fmaf( g1i, t1r, p1i));                   \
            float n0r = t0r * r0r - t0i * r0i;                            \
            float n0i = t0r * r0i + t0i * r0r;                            \
            float n1r = t1r * r1r - t1i * r1i;                            \
            float n1i = t1r * r1i + t1i * r1r;                            \
            t0r = n0r; t0i = n0i; t1r = n1r; t1i = n1i; }
        PROC_(q0.x, q1.x, q2.x, q3.x)
        PROC_(q0.y, q1.y, q2.y, q3.y)
        PROC_(q0.z, q1.z, q2.z, q3.z)
        PROC_(q0.w, q1.w, q2.w, q3.w)
        #undef PROC_
    }
    int y = ch * 32 + rowc;
    ((float4*)P)[((size_t)bc * 256 + y) * 8 + h] = make_float4(p0r, p0i, p1r, p1i);
}

// y-DFT. grid 2048 = (bc, half). Half hh sums yy in [32hh, 32hh+32) of the
// quarter-turn groups (y = yy+64g); U = U0 + U1 exactly. Seed phase
// e^{-2pi i f*32hh/256} is identical for f=m1 and f=m1-16 (mod 256).
__global__ __launch_bounds__(256) void k_fwd2(const float* __restrict__ P,
                                              float* __restrict__ ws) {
    __shared__ float Pl[4][32][36];                  // 18.4 KB
    int t = threadIdx.x;
    int bc = blockIdx.x >> 1, hh = blockIdx.x & 1;
    const float4* Pg = (const float4*)(P + (size_t)bc * 8192);
    #pragma unroll
    for (int k = 0; k < 4; ++k) {
        int idx = t + 256 * k;                       // 0..1023
        int g = idx >> 8, j = (idx >> 3) & 31, q = idx & 7;
        *(float4*)&Pl[g][j][4 * q] = Pg[(size_t)(hh * 32 + j + 64 * g) * 8 + q];
    }
    __syncthreads();

    int wm = t & 15;
    int v  = t >> 4;
    int m1 = ((v & 3) << 2) | (v >> 2);              // md = m1&3 uniform per wave
    float sv, cv;
    __sincosf(TWOPI_256 * (float)m1, &sv, &cv);
    float r1r = cv, r1i = -sv;                       // e^{-2pi i m1/256}
    __sincosf(TWOPI_256 * (float)(m1 - 16), &sv, &cv);
    float r2r = cv, r2i = -sv;                       // e^{-2pi i (m1-16)/256}
    int a0 = (m1 * 32 * hh) & 255;                   // seed phase (both modes)
    __sincosf(TWOPI_256 * (float)a0, &sv, &cv);
    float t1r = cv, t1i = -sv, t2r = cv, t2i = -sv;
    float U1r = 0.f, U1i = 0.f, U2r = 0.f, U2i = 0.f;
    int md = m1 & 3;
    #pragma unroll 4
    for (int j = 0; j < 32; ++j) {
        float2 P0 = *(float2*)&Pl[0][j][2 * wm];
        float2 P1 = *(float2*)&Pl[1][j][2 * wm];
        float2 P2 = *(float2*)&Pl[2][j][2 * wm];
        float2 P3 = *(float2*)&Pl[3][j][2 * wm];
        float ar = P0.x + P2.x, ai = P0.y + P2.y;
        float br = P1.x + P3.x, bi = P1.y + P3.y;
        float cr = P0.x - P2.x, ci = P0.y - P2.y;
        float dr = P1.x - P3.x, di = P1.y - P3.y;
        float gr, gi;
        if (md == 0)      { gr = ar + br; gi = ai + bi; }
        else if (md == 1) { gr = cr + di; gi = ci - dr; }   // g = c - i d
        else if (md == 2) { gr = ar - br; gi = ai - bi; }
        else              { gr = cr - di; gi = ci + dr; }   // g = c + i d
        U1r = fmaf(gr, t1r, fmaf(-gi, t1i, U1r));
        U1i = fmaf(gr, t1i, fmaf( gi, t1r, U1i));
        U2r = fmaf(gr, t2r, fmaf(-gi, t2i, U2r));
        U2i = fmaf(gr, t2i, fmaf( gi, t2r, U2i));
        float n1r = t1r * r1r - t1i * r1i, n1i = t1r * r1i + t1i * r1r;
        float n2r = t2r * r2r - t2i * r2i, n2i = t2r * r2i + t2i * r2r;
        t1r = n1r; t1i = n1i; t2r = n2r; t2i = n2i;
    }
    float2* U = (float2*)(ws + (hh ? OFF_U1 : OFF_U0)) + (size_t)bc * 512;
    U[m1 * 16 + wm]        = make_float2(U1r, U1i);
    U[(m1 + 16) * 16 + wm] = make_float2(U2r, U2i);
}

// per-mode channel GEMM: grid 512 = mw. Combines U = U0 + U1 on load.
__global__ __launch_bounds__(256) void k_cgemm(float* __restrict__ ws) {
    __shared__ float2 Ul[1024];
    int mw = blockIdx.x, t = threadIdx.x;
    const float2* Ug0 = (const float2*)(ws + OFF_U0);
    const float2* Ug1 = (const float2*)(ws + OFF_U1);
    #pragma unroll
    for (int k = 0; k < 4; ++k) {
        int bcv = t + 256 * k;
        float2 a = Ug0[(size_t)bcv * 512 + mw];
        float2 b = Ug1[(size_t)bcv * 512 + mw];
        Ul[bcv] = make_float2(a.x + b.x, a.y + b.y);
    }
    __syncthreads();
    int o = t & 63, bq = t >> 6;
    const float2* rp = (const float2*)(ws + OFF_RP) + (size_t)mw * 4096;  // [mw][co]
    float ar[4] = {0.f, 0.f, 0.f, 0.f}, ai[4] = {0.f, 0.f, 0.f, 0.f};
    #pragma unroll 4
    for (int c = 0; c < 64; ++c) {
        float2 R = rp[c * 64 + o];                         // coalesced 512B
        #pragma unroll
        for (int j = 0; j < 4; ++j) {
            float2 Uv = Ul[(bq * 4 + j) * 64 + c];         // wave-uniform -> broadcast
            ar[j] = fmaf(Uv.x, R.x, fmaf(-Uv.y, R.y, ar[j]));
            ai[j] = fmaf(Uv.x, R.y, fmaf( Uv.y, R.x, ai[j]));
        }
    }
    float2* Vg = (float2*)(ws + OFF_V) + (size_t)mw * 1024;  // [mw][bo]
    #pragma unroll
    for (int j = 0; j < 4; ++j)
        Vg[(bq * 4 + j) * 64 + o] = make_float2(ar[j], ai[j]);  // coalesced
}

// inverse. grid 4096 = (bo, q). Stage 5 quad-symmetric (R13, verified).
__global__ __launch_bounds__(256) void k_inv(const float* __restrict__ ws,
                                             float* __restrict__ out) {
    __shared__ float Vl[16][68];
    __shared__ float Tl[4][16][36];
    __shared__ float ct[256], st[256];
    int t = threadIdx.x;
    int bo = blockIdx.x >> 2, q = blockIdx.x & 3;
    ct[t] = ws[OFF_CT + t];
    st[t] = ws[OFF_ST + t];
    {
        const float2* Vg = (const float2*)(ws + OFF_V);
        float2 v0 = Vg[(size_t)t * 1024 + bo];
        float2 v1 = Vg[(size_t)(t + 256) * 1024 + bo];
        int m = t >> 4, wmv = t & 15;
        Vl[wmv][2 * m]        = v0.x;  Vl[wmv][2 * m + 1]        = v0.y;
        Vl[wmv][2 * (m + 16)] = v1.x;  Vl[wmv][2 * (m + 16) + 1] = v1.y;
    }
    __syncthreads();

    // stage 4: T[y0+64g] = sum_m V[m] e^{+2pi i f y0/256} * i^(f g)
    int wm4 = t & 15, yb = t >> 4;
    int y0 = q * 16 + yb;
    float vr[32], vi[32];
    #pragma unroll
    for (int m = 0; m < 32; ++m) { vr[m] = Vl[wm4][2 * m]; vi[m] = Vl[wm4][2 * m + 1]; }
    float cy = ct[y0], sy = st[y0];
    float T0r=0,T0i=0,T1r=0,T1i=0,T2r=0,T2i=0,T3r=0,T3i=0;
    float tr = 1.f, ti = 0.f;
    #pragma unroll
    for (int m = 0; m < 32; ++m) {
        if (m == 16) {
            int i16 = (4096 - 16 * y0) & 255;          // e^{-2pi i 16 y0/256}
            tr = ct[i16]; ti = st[i16];
        }
        float hr = vr[m] * tr - vi[m] * ti;
        float hi = vr[m] * ti + vi[m] * tr;
        const int md = m & 3;
        T0r += hr; T0i += hi;
        if (md == 0)      { T1r += hr; T1i += hi; T2r += hr; T2i += hi; T3r += hr; T3i += hi; }
        else if (md == 1) { T1r -= hi; T1i += hr; T2r -= hr; T2i -= hi; T3r += hi; T3i -= hr; }
        else if (md == 2) { T1r -= hr; T1i -= hi; T2r += hr; T2i += hi; T3r -= hr; T3i -= hi; }
        else              { T1r += hi; T1i -= hr; T2r -= hr; T2i -= hi; T3r -= hi; T3i += hr; }
        float nr = tr * cy - ti * sy, ni = tr * sy + ti * cy;
        tr = nr; ti = ni;
    }
    Tl[0][yb][wm4] = T0r; Tl[0][yb][16 + wm4] = T0i;
    Tl[1][yb][wm4] = T1r; Tl[1][yb][16 + wm4] = T1i;
    Tl[2][yb][wm4] = T2r; Tl[2][yb][16 + wm4] = T2i;
    Tl[3][yb][wm4] = T3r; Tl[3][yb][16 + wm4] = T3i;
    __syncthreads();

    // stage 5: quad-symmetric x reconstruction
    int l = t & 63, wv = t >> 6;
    float c0[16], s0[16];
    #pragma unroll
    for (int wm = 0; wm < 16; ++wm) {
        int idx = (wm * l) & 255;
        c0[wm] = ct[idx]; s0[wm] = st[idx];
    }
    float* ob = out + (size_t)bo * 65536;
    for (int yi = 0; yi < 16; ++yi) {
        int y = wv * 64 + q * 16 + yi;
        float TR[16], TI[16];
        const float4* rowv = (const float4*)&Tl[wv][yi][0];
        #pragma unroll
        for (int qq = 0; qq < 4; ++qq) {
            float4 a = rowv[qq];
            TR[4*qq]=a.x; TR[4*qq+1]=a.y; TR[4*qq+2]=a.z; TR[4*qq+3]=a.w;
            float4 b = rowv[qq + 4];
            TI[4*qq]=b.x; TI[4*qq+1]=b.y; TI[4*qq+2]=b.z; TI[4*qq+3]=b.w;
        }
        float Pv = 0.f, Qv = 0.f, Rv = 0.f, Sv = 0.f;
        #pragma unroll
        for (int wm = 0; wm < 16; wm += 2) {
            Pv = fmaf(TR[wm],     c0[wm],     Pv);
            Rv = fmaf(TI[wm],     s0[wm],     Rv);
            Qv = fmaf(TR[wm + 1], c0[wm + 1], Qv);
            Sv = fmaf(TI[wm + 1], s0[wm + 1], Sv);
        }
        float Ac = Pv + Qv, Bs = Rv + Sv;
        float Dc = Pv - Qv, Es = Rv - Sv;
        float* row = ob + (size_t)y * 256;
        row[l]               = Ac - Bs;        // x = l
        row[(256 - l) & 255] = Ac + Bs;        // x = 256-l
        row[128 + l]         = Dc - Es;        // x = 128+l
        row[128 - l]         = Dc + Es;        // x = 128-l
        float E0 = TR[0] + TR[4] + TR[8]  + TR[12];
        float E2 = TR[2] + TR[6] + TR[10] + TR[14];
        float O1 = TI[1] + TI[5] + TI[9]  + TI[13];
        float O3 = TI[3] + TI[7] + TI[11] + TI[15];
        float EC = E0 - E2, OC = O1 - O3;
        if (l == 0) {
            row[64]  = EC - OC;
            row[192] = EC + OC;
        }
    }
}

extern "C" void kernel_launch(void* const* d_in, const int* in_sizes, int n_in,
                              void* d_out, int out_size, void* d_ws, size_t ws_size,
                              hipStream_t stream) {
    const float* u   = (const float*)d_in[0];
    const float* wpr = (const float*)d_in[1];
    const float* wpi = (const float*)d_in[2];
    const float* wnr = (const float*)d_in[3];
    const float* wni = (const float*)d_in[4];
    float* out = (float*)d_out;
    float* ws  = (float*)d_ws;
    float* P   = (float*)d_out;            // 33.5 MB scratch in d_out (overwritten by k_inv)

    hipLaunchKernelGGL(k_fwd1,  dim3(8704), dim3(256), 0, stream, u, wpr, wpi, wnr, wni, ws, P);
    hipLaunchKernelGGL(k_fwd2,  dim3(2048), dim3(256), 0, stream, P, ws);
    hipLaunchKernelGGL(k_cgemm, dim3(512),  dim3(256), 0, stream, ws);
    hipLaunchKernelGGL(k_inv,   dim3(4096), dim3(256), 0, stream, ws, out);
}

// Round 17
// 204.450 us; speedup vs baseline: 1.1404x; 1.0325x over previous
//
#include <hip/hip_runtime.h>

// SpectralConv2d: B=16, C_in=C_out=64, H=W=256, k=16.
// Retained modes: rows {0..15, 240..255} x cols {0..15} -> direct sparse DFTs.
//
// Pipeline (fp32):
//  k_fwd1    : x-DFT per (b,c,chunk): seg-split lanes (r8,h,s) — each lane reads
//              ONLY its quarter-row seg (16 b128, 4x fewer LDS instr), computes
//              8 modes with scalar-only state, DPP quad-butterfly over s, s==0
//              writes P. [blocks 0..8191] + repack R'[mw][co] [8192..8703].
//  k_fwd2    : y-DFT onto 32 row modes -> U[bc][mw]   (R13 verbatim)
//  k_cgemm   : per mw: V[mw][bo] = sum_c U[b][c]*R'[c][o]  (R13 verbatim)
//  k_inv     : inverse y-DFT + quad-symmetric x reconstruction (R13 verbatim)

// ws float offsets (R13 map)
#define OFF_CT 0
#define OFF_ST 256
#define OFF_RP 512
#define RP_SZ  (512*4096*2)                  // 4,194,304 floats ([mw][co] float2)
#define OFF_U  (OFF_RP + RP_SZ)              // 4,194,816  ([bc][mw] float2)
#define U_SZ   (1024*512*2)                  // 1,048,576
#define OFF_V  (OFF_U + U_SZ)                // 5,243,392  ([mw][bo] float2)

#define UTP   260                            // ut row pitch (floats)
#define TWOPI_256 0.024543692606170259f      // 2*pi/256

typedef const __attribute__((address_space(1))) void g_void;
typedef __attribute__((address_space(3))) void l_void;

__device__ __forceinline__ void load_lds16(const float* g, float* l) {
    __builtin_amdgcn_global_load_lds((g_void*)g, (l_void*)l, 16, 0, 0);
}

// DPP lane-permute: 0xB1 = quad_perm xor1, 0x4E = quad_perm xor2 (verified R6).
template<int CTRL>
__device__ __forceinline__ float dppf(float x) {
    return __int_as_float(__builtin_amdgcn_update_dpp(
        0, __float_as_int(x), CTRL, 0xF, 0xF, true));
}

// x-DFT + repack. grid 8704: blocks 0..8191 = (bc,chunk) x-DFT; 8192.. = repack.
__global__ __launch_bounds__(256) void k_fwd1(const float* __restrict__ u,
                                              const float* __restrict__ wpr,
                                              const float* __restrict__ wpi,
                                              const float* __restrict__ wnr,
                                              const float* __restrict__ wni,
                                              float* __restrict__ ws,
                                              float* __restrict__ P) {
    __shared__ __align__(16) float ut[32][UTP];      // 33.3 KB
    int t = threadIdx.x;

    if (blockIdx.x >= 8192) {                        // ---- repack branch ----
        int mw = blockIdx.x - 8192;                  // 0..511 = m*16 + wmc
        int m = mw >> 4, wmc = mw & 15;
        const float* wr; const float* wi; int i;
        if (m < 16) { wr = wpr; wi = wpi; i = m; }
        else        { wr = wnr; wi = wni; i = m - 16; }
        if (mw == 0) {                               // twiddle tables for k_inv
            double a = 2.0 * 3.14159265358979323846 * (double)t / 256.0;
            ws[OFF_CT + t] = (float)cos(a);
            ws[OFF_ST + t] = (float)sin(a);
        }
        float norm = (wmc == 0 ? 1.f : 2.f) * (1.f / 65536.f);
        int off = i * 16 + wmc;
        float2* rp = (float2*)(ws + OFF_RP) + (size_t)mw * 4096;
        #pragma unroll
        for (int k = 0; k < 16; ++k) {
            int co = t + 256 * k;
            rp[co] = make_float2(wr[(size_t)co * 256 + off] * norm,
                                 wi[(size_t)co * 256 + off] * norm);
        }
        return;
    }

    int bc = blockIdx.x >> 3, ch = blockIdx.x & 7;
    const float* ub = u + (size_t)bc * 65536 + ch * 8192;
    int lane = t & 63, w = t >> 6;
    #pragma unroll
    for (int k = 0; k < 8; ++k)
        load_lds16(ub + (w * 8 + k) * 256 + lane * 4, &ut[w * 8 + k][0]);

    // lane decomposition: s = seg (j in [16s,16s+16)), h = mode-half (wm 8h..8h+7),
    // r8 = row within wave's 8 rows.
    int s = lane & 3, h = (lane >> 2) & 1, r8 = lane >> 3;
    int rowc = w * 8 + r8;

    // twiddle seeds (scalar state only)
    float sv, cv;
    __sincosf(TWOPI_256 * 1.f, &sv, &cv);
    float rb1r = cv, rb1i = -sv;                         // e^{-i th}
    __sincosf(TWOPI_256 * (float)(8 * h), &sv, &cv);
    float r8hr = cv, r8hi = -sv;                         // e^{-i th 8h}
    int j0 = 16 * s;
    __sincosf(TWOPI_256 * (float)((8 * h * j0) & 255), &sv, &cv);
    float tw0r = cv, tw0i = -sv;                         // e^{-i th 8h j0}
    __sincosf(TWOPI_256 * (float)j0, &sv, &cv);
    float bjr = cv, bji = -sv;                           // e^{-i th j0}

    float a0r=0,a0i=0,a1r=0,a1i=0,a2r=0,a2i=0,a3r=0,a3i=0;
    float a4r=0,a4i=0,a5r=0,a5i=0,a6r=0,a6i=0,a7r=0,a7i=0;

    // wait ONLY this wave's 8 staging loads
    asm volatile("s_waitcnt vmcnt(0)" ::: "memory");

    const float* q0p = &ut[rowc][j0];
    #define CMUL_(tr_, ti_) { float nr_ = tr_*bjr - ti_*bji,                \
          ni_ = tr_*bji + ti_*bjr; tr_ = nr_; ti_ = ni_; }
    #define STEP_(u0,u1,u2,u3) {                                            \
        float Av_=(u0)+(u2), Bv_=(u1)+(u3), Cv_=(u0)-(u2), Dv_=(u1)-(u3);   \
        float gp_ = Av_ + Bv_, gm_ = Av_ - Bv_;                             \
        float twr = tw0r, twi = tw0i;                                       \
        a0r = fmaf(gp_, twr, a0r); a0i = fmaf(gp_, twi, a0i);               \
        CMUL_(twr, twi)                                                     \
        a1r = fmaf(Cv_, twr, fmaf( Dv_, twi, a1r));                         \
        a1i = fmaf(Cv_, twi, fmaf(-Dv_, twr, a1i));                         \
        CMUL_(twr, twi)                                                     \
        a2r = fmaf(gm_, twr, a2r); a2i = fmaf(gm_, twi, a2i);               \
        CMUL_(twr, twi)                                                     \
        a3r = fmaf(Cv_, twr, fmaf(-Dv_, twi, a3r));                         \
        a3i = fmaf(Cv_, twi, fmaf( Dv_, twr, a3i));                         \
        CMUL_(twr, twi)                                                     \
        a4r = fmaf(gp_, twr, a4r); a4i = fmaf(gp_, twi, a4i);               \
        CMUL_(twr, twi)                                                     \
        a5r = fmaf(Cv_, twr, fmaf( Dv_, twi, a5r));                         \
        a5i = fmaf(Cv_, twi, fmaf(-Dv_, twr, a5i));                         \
        CMUL_(twr, twi)                                                     \
        a6r = fmaf(gm_, twr, a6r); a6i = fmaf(gm_, twi, a6i);               \
        CMUL_(twr, twi)                                                     \
        a7r = fmaf(Cv_, twr, fmaf(-Dv_, twi, a7r));                         \
        a7i = fmaf(Cv_, twi, fmaf( Dv_, twr, a7i));                         \
        { float nr = tw0r*r8hr - tw0i*r8hi, ni = tw0r*r8hi + tw0i*r8hr;     \
          tw0r = nr; tw0i = ni; }                                           \
        { float nr = bjr*rb1r - bji*rb1i, ni = bjr*rb1i + bji*rb1r;         \
          bjr = nr; bji = ni; } }

    #pragma unroll
    for (int g = 0; g < 4; ++g) {                    // 4 float4 per quarter-run
        float4 x0 = *(const float4*)(q0p + 4 * g);
        float4 x1 = *(const float4*)(q0p + 64  + 4 * g);
        float4 x2 = *(const float4*)(q0p + 128 + 4 * g);
        float4 x3 = *(const float4*)(q0p + 192 + 4 * g);
        STEP_(x0.x, x1.x, x2.x, x3.x)
        STEP_(x0.y, x1.y, x2.y, x3.y)
        STEP_(x0.z, x1.z, x2.z, x3.z)
        STEP_(x0.w, x1.w, x2.w, x3.w)
    }
    #undef STEP_
    #undef CMUL_

    // butterfly over the 4 s-lanes (quad_perm xor1 + xor2): all lanes get the sum
    #define RED_(v) { v += dppf<0xB1>(v); v += dppf<0x4E>(v); }
    RED_(a0r) RED_(a0i) RED_(a1r) RED_(a1i)
    RED_(a2r) RED_(a2i) RED_(a3r) RED_(a3i)
    RED_(a4r) RED_(a4i) RED_(a5r) RED_(a5i)
    RED_(a6r) RED_(a6i) RED_(a7r) RED_(a7i)
    #undef RED_

    if ((lane & 3) == 0) {
        int y = ch * 32 + rowc;
        float4* Pp = (float4*)P + (((size_t)bc * 256 + y) * 8 + 4 * h);
        Pp[0] = make_float4(a0r, a0i, a1r, a1i);     // wm 8h+0, 8h+1
        Pp[1] = make_float4(a2r, a2i, a3r, a3i);     // wm 8h+2, 8h+3
        Pp[2] = make_float4(a4r, a4i, a5r, a5i);     // wm 8h+4, 8h+5
        Pp[3] = make_float4(a6r, a6i, a7r, a7i);     // wm 8h+6, 8h+7
    }
}

// y-DFT. grid 1024 = bc. y = yy + 64k quarter-turn; md = m1&3 wave-uniform via remap.
// U write coalesced into [bc][mw] layout. (R13 verbatim)
__global__ __launch_bounds__(256) void k_fwd2(const float* __restrict__ P,
                                              float* __restrict__ ws) {
    __shared__ float Pl[256][36];
    int t = threadIdx.x, bc = blockIdx.x;
    const float4* Pg = (const float4*)(P + (size_t)bc * 8192);
    #pragma unroll
    for (int k = 0; k < 8; ++k) {
        int f4 = t + 256 * k;
        int y = f4 >> 3, q = f4 & 7;
        *(float4*)&Pl[y][q * 4] = Pg[f4];
    }
    __syncthreads();

    int wm = t & 15;
    int v  = t >> 4;
    int m1 = ((v & 3) << 2) | (v >> 2);               // md = m1&3 uniform per wave
    float sv, cv;
    __sincosf(TWOPI_256 * (float)m1, &sv, &cv);
    float r1r = cv, r1i = -sv;                        // e^{-2pi i m1/256}
    __sincosf(TWOPI_256 * (float)(m1 - 16), &sv, &cv);
    float r2r = cv, r2i = -sv;                        // e^{-2pi i (m1-16)/256}
    float t1r = 1.f, t1i = 0.f, t2r = 1.f, t2i = 0.f;
    float U1r = 0.f, U1i = 0.f, U2r = 0.f, U2i = 0.f;
    int md = m1 & 3;
    #pragma unroll 4
    for (int yy = 0; yy < 64; ++yy) {
        float2 P0 = *(float2*)&Pl[yy][2 * wm];
        float2 P1 = *(float2*)&Pl[yy + 64][2 * wm];
        float2 P2 = *(float2*)&Pl[yy + 128][2 * wm];
        float2 P3 = *(float2*)&Pl[yy + 192][2 * wm];
        float ar = P0.x + P2.x, ai = P0.y + P2.y;
        float br = P1.x + P3.x, bi = P1.y + P3.y;
        float cr = P0.x - P2.x, ci = P0.y - P2.y;
        float dr = P1.x - P3.x, di = P1.y - P3.y;
        float gr, gi;
        if (md == 0)      { gr = ar + br; gi = ai + bi; }
        else if (md == 1) { gr = cr + di; gi = ci - dr; }   // g = c - i d
        else if (md == 2) { gr = ar - br; gi = ai - bi; }
        else              { gr = cr - di; gi = ci + dr; }   // g = c + i d
        U1r = fmaf(gr, t1r, fmaf(-gi, t1i, U1r));
        U1i = fmaf(gr, t1i, fmaf( gi, t1r, U1i));
        U2r = fmaf(gr, t2r, fmaf(-gi, t2i, U2r));
        U2i = fmaf(gr, t2i, fmaf( gi, t2r, U2i));
        float n1r = t1r * r1r - t1i * r1i, n1i = t1r * r1i + t1i * r1r;
        float n2r = t2r * r2r - t2i * r2i, n2i = t2r * r2i + t2i * r2r;
        t1r = n1r; t1i = n1i; t2r = n2r; t2i = n2i;
    }
    float2* U = (float2*)(ws + OFF_U) + (size_t)bc * 512;   // [bc][mw]
    U[m1 * 16 + wm]          = make_float2(U1r, U1i);       // 128B segments
    U[(m1 + 16) * 16 + wm]   = make_float2(U2r, U2i);
}

// per-mode channel GEMM: grid 512 = mw. U scatter-read (L3), R'/V coalesced. (R13)
__global__ __launch_bounds__(256) void k_cgemm(float* __restrict__ ws) {
    __shared__ float2 Ul[1024];
    int mw = blockIdx.x, t = threadIdx.x;
    const float2* Ug = (const float2*)(ws + OFF_U);
    #pragma unroll
    for (int k = 0; k < 4; ++k) {
        int bcv = t + 256 * k;
        Ul[bcv] = Ug[(size_t)bcv * 512 + mw];              // stride-512 scatter (L3)
    }
    __syncthreads();
    int o = t & 63, bq = t >> 6;
    const float2* rp = (const float2*)(ws + OFF_RP) + (size_t)mw * 4096;  // [mw][co]
    float ar[4] = {0.f, 0.f, 0.f, 0.f}, ai[4] = {0.f, 0.f, 0.f, 0.f};
    #pragma unroll 4
    for (int c = 0; c < 64; ++c) {
        float2 R = rp[c * 64 + o];                         // coalesced 512B
        #pragma unroll
        for (int j = 0; j < 4; ++j) {
            float2 Uv = Ul[(bq * 4 + j) * 64 + c];         // wave-uniform -> broadcast
            ar[j] = fmaf(Uv.x, R.x, fmaf(-Uv.y, R.y, ar[j]));
            ai[j] = fmaf(Uv.x, R.y, fmaf( Uv.y, R.x, ai[j]));
        }
    }
    float2* Vg = (float2*)(ws + OFF_V) + (size_t)mw * 1024;  // [mw][bo]
    #pragma unroll
    for (int j = 0; j < 4; ++j)
        Vg[(bq * 4 + j) * 64 + o] = make_float2(ar[j], ai[j]);  // coalesced
}

// inverse. grid 4096 = (bo, q). Stage 5 quad-symmetric (R13 verbatim).
__global__ __launch_bounds__(256) void k_inv(const float* __restrict__ ws,
                                             float* __restrict__ out) {
    __shared__ float Vl[16][68];
    __shared__ float Tl[4][16][36];
    __shared__ float ct[256], st[256];
    int t = threadIdx.x;
    int bo = blockIdx.x >> 2, q = blockIdx.x & 3;
    ct[t] = ws[OFF_CT + t];
    st[t] = ws[OFF_ST + t];
    {
        const float2* Vg = (const float2*)(ws + OFF_V);
        float2 v0 = Vg[(size_t)t * 1024 + bo];
        float2 v1 = Vg[(size_t)(t + 256) * 1024 + bo];
        int m = t >> 4, wmv = t & 15;
        Vl[wmv][2 * m]        = v0.x;  Vl[wmv][2 * m + 1]        = v0.y;
        Vl[wmv][2 * (m + 16)] = v1.x;  Vl[wmv][2 * (m + 16) + 1] = v1.y;
    }
    __syncthreads();

    // stage 4: T[y0+64g] = sum_m V[m] e^{+2pi i f y0/256} * i^(f g)
    int wm4 = t & 15, yb = t >> 4;
    int y0 = q * 16 + yb;
    float vr[32], vi[32];
    #pragma unroll
    for (int m = 0; m < 32; ++m) { vr[m] = Vl[wm4][2 * m]; vi[m] = Vl[wm4][2 * m + 1]; }
    float cy = ct[y0], sy = st[y0];
    float T0r=0,T0i=0,T1r=0,T1i=0,T2r=0,T2i=0,T3r=0,T3i=0;
    float tr = 1.f, ti = 0.f;
    #pragma unroll
    for (int m = 0; m < 32; ++m) {
        if (m == 16) {
            int i16 = (4096 - 16 * y0) & 255;          // e^{-2pi i 16 y0/256}
            tr = ct[i16]; ti = st[i16];
        }
        float hr = vr[m] * tr - vi[m] * ti;
        float hi = vr[m] * ti + vi[m] * tr;
        const int md = m & 3;
        T0r += hr; T0i += hi;
        if (md == 0)      { T1r += hr; T1i += hi; T2r += hr; T2i += hi; T3r += hr; T3i += hi; }
        else if (md == 1) { T1r -= hi; T1i += hr; T2r -= hr; T2i -= hi; T3r += hi; T3i -= hr; }
        else if (md == 2) { T1r -= hr; T1i -= hi; T2r += hr; T2i += hi; T3r -= hr; T3i -= hi; }
        else              { T1r += hi; T1i -= hr; T2r -= hr; T2i -= hi; T3r -= hi; T3i += hr; }
        float nr = tr * cy - ti * sy, ni = tr * sy + ti * cy;
        tr = nr; ti = ni;
    }
    Tl[0][yb][wm4] = T0r; Tl[0][yb][16 + wm4] = T0i;
    Tl[1][yb][wm4] = T1r; Tl[1][yb][16 + wm4] = T1i;
    Tl[2][yb][wm4] = T2r; Tl[2][yb][16 + wm4] = T2i;
    Tl[3][yb][wm4] = T3r; Tl[3][yb][16 + wm4] = T3i;
    __syncthreads();

    // stage 5: quad-symmetric x reconstruction
    int l = t & 63, wv = t >> 6;
    float c0[16], s0[16];
    #pragma unroll
    for (int wm = 0; wm < 16; ++wm) {
        int idx = (wm * l) & 255;
        c0[wm] = ct[idx]; s0[wm] = st[idx];
    }
    float* ob = out + (size_t)bo * 65536;
    for (int yi = 0; yi < 16; ++yi) {
        int y = wv * 64 + q * 16 + yi;
        float TR[16], TI[16];
        const float4* rowv = (const float4*)&Tl[wv][yi][0];
        #pragma unroll
        for (int qq = 0; qq < 4; ++qq) {
            float4 a = rowv[qq];
            TR[4*qq]=a.x; TR[4*qq+1]=a.y; TR[4*qq+2]=a.z; TR[4*qq+3]=a.w;
            float4 b = rowv[qq + 4];
            TI[4*qq]=b.x; TI[4*qq+1]=b.y; TI[4*qq+2]=b.z; TI[4*qq+3]=b.w;
        }
        float Pv = 0.f, Qv = 0.f, Rv = 0.f, Sv = 0.f;
        #pragma unroll
        for (int wm = 0; wm < 16; wm += 2) {
            Pv = fmaf(TR[wm],     c0[wm],     Pv);
            Rv = fmaf(TI[wm],     s0[wm],     Rv);
            Qv = fmaf(TR[wm + 1], c0[wm + 1], Qv);
            Sv = fmaf(TI[wm + 1], s0[wm + 1], Sv);
        }
        float Ac = Pv + Qv, Bs = Rv + Sv;
        float Dc = Pv - Qv, Es = Rv - Sv;
        float* row = ob + (size_t)y * 256;
        row[l]               = Ac - Bs;        // x = l
        row[(256 - l) & 255] = Ac + Bs;        // x = 256-l
        row[128 + l]         = Dc - Es;        // x = 128+l
        row[128 - l]         = Dc + Es;        // x = 128-l
        float E0 = TR[0] + TR[4] + TR[8]  + TR[12];
        float E2 = TR[2] + TR[6] + TR[10] + TR[14];
        float O1 = TI[1] + TI[5] + TI[9]  + TI[13];
        float O3 = TI[3] + TI[7] + TI[11] + TI[15];
        float EC = E0 - E2, OC = O1 - O3;
        if (l == 0) {
            row[64]  = EC - OC;
            row[192] = EC + OC;
        }
    }
}

extern "C" void kernel_launch(void* const* d_in, const int* in_sizes, int n_in,
                              void* d_out, int out_size, void* d_ws, size_t ws_size,
                              hipStream_t stream) {
    const float* u   = (const float*)d_in[0];
    const float* wpr = (const float*)d_in[1];
    const float* wpi = (const float*)d_in[2];
    const float* wnr = (const float*)d_in[3];
    const float* wni = (const float*)d_in[4];
    float* out = (float*)d_out;
    float* ws  = (float*)d_ws;
    float* P   = (float*)d_out;            // 33.5 MB scratch in d_out (overwritten by k_inv)

    hipLaunchKernelGGL(k_fwd1,  dim3(8704), dim3(256), 0, stream, u, wpr, wpi, wnr, wni, ws, P);
    hipLaunchKernelGGL(k_fwd2,  dim3(1024), dim3(256), 0, stream, P, ws);
    hipLaunchKernelGGL(k_cgemm, dim3(512),  dim3(256), 0, stream, ws);
    hipLaunchKernelGGL(k_inv,   dim3(4096), dim3(256), 0, stream, ws, out);
}